// Round 11
// baseline (492.145 us; speedup 1.0000x reference)
//
#include <hip/hip_runtime.h>
#include <hip/hip_bf16.h>
#include <cstdint>
#include <cstddef>

#define NN 8192
#define FIN 128
#define FOUT 64

typedef __attribute__((ext_vector_type(8))) short short8;
typedef __attribute__((ext_vector_type(4))) float f32x4;

__device__ __forceinline__ unsigned short f32_to_bf16_bits(float f) {
    union { float f; uint32_t u; } c; c.f = f;
    uint32_t u = c.u;
    u += 0x7fffu + ((u >> 16) & 1u);   // RNE
    return (unsigned short)(u >> 16);
}

// Kernel 1: Wh = x @ W^T (bf16, stored transposed [f][i]); Wh1 = Wh@a1; Wh2 = Wh@a2
__global__ __launch_bounds__(256) void gat_prep(
    const float* __restrict__ x, const float* __restrict__ W,
    const float* __restrict__ a, unsigned short* __restrict__ WhT,
    float* __restrict__ Wh1, float* __restrict__ Wh2)
{
    const int t    = threadIdx.x;
    const int f    = t & 63;        // lane = feature
    const int iloc = t >> 6;        // wave = local row
    const int i    = blockIdx.x * 4 + iloc;

    const float4* x4 = (const float4*)(x + (size_t)i * FIN);  // wave-uniform
    const float4* w4 = (const float4*)(W + (size_t)f * FIN);

    float acc = 0.f;
#pragma unroll
    for (int k = 0; k < FIN / 4; ++k) {
        float4 xv = x4[k];
        float4 wv = w4[k];
        acc += xv.x * wv.x + xv.y * wv.y + xv.z * wv.z + xv.w * wv.w;
    }

    WhT[(size_t)f * NN + i] = f32_to_bf16_bits(acc);

    float r1 = acc * a[f];
    float r2 = acc * a[64 + f];
#pragma unroll
    for (int m = 1; m < 64; m <<= 1) {
        r1 += __shfl_xor(r1, m, 64);
        r2 += __shfl_xor(r2, m, 64);
    }
    if (f == 0) { Wh1[i] = r1; Wh2[i] = r2; }
}

// Kernel 1b: adj (int32, 268 MB) -> bitmask (8 MB), PERFECTLY LINEAR read.
// R9 post-mortem: attn's striped 128B-granule adj pattern ran at <50% HBM
// efficiency and resisted every schedule fix. This kernel reads adj exactly
// like the 84%-of-peak fill (wave = 64 consecutive ints = 256B/inst) and
// emits one uint64 per 64 entries via ballot. mask[i*128+g] bit l =
// adj[i][g*64+l] > 0. 8192 waves, each 32 KB contiguous.
__global__ __launch_bounds__(256) void gat_pack(
    const int* __restrict__ adj, unsigned long long* __restrict__ mask)
{
    const int lane = threadIdx.x & 63;
    const int wv   = (int)((blockIdx.x * 256 + threadIdx.x) >> 6); // 0..8191
    const size_t w0 = (size_t)wv * 128;
#pragma unroll 8
    for (int k = 0; k < 128; ++k) {
        const size_t w = w0 + k;
        const int v = adj[w * 64 + lane];
        const unsigned long long b = __ballot(v > 0);
        if (lane == 0) mask[w] = b;
    }
}

// Kernel 2 (fused, 32-row blocks, bitmask adj): 256 blocks x 1024 threads
// (16 waves), 1 block/CU. Each block owns a 32-row panel, full j range;
// wave w covers j-strip [w*32 + tt*512, +32) for tt=0..15.
// adj HBM traffic in this kernel: 32 KB/block (bitmask) vs 1 MB before.
// All loads (mask/Wh2/B) JIT - L1/L2-hot, TLP covers. ~90 VGPR, no spill.
__global__ __launch_bounds__(1024, 4) void gat_attn(
    const unsigned long long* __restrict__ mask,
    const unsigned short* __restrict__ WhT,
    const float* __restrict__ Wh1, const float* __restrict__ Wh2,
    float* __restrict__ out)
{
    __shared__ float lds_C[16][32][66];   // pad 64->66: 2-way (free) aliasing
    __shared__ float lds_tot[16][32];

    const int tid  = threadIdx.x;
    const int wave = tid >> 6;       // 0..15
    const int lane = tid & 63;
    const int il   = lane & 15;      // A-fragment row within 16-row group
    const int q    = lane >> 4;      // quad -> k offset q*8
    const int i0   = blockIdx.x * 32;
    const int iA   = i0 + il;        // rows 0..15
    const int iB   = i0 + 16 + il;   // rows 16..31

    const float wh1A = Wh1[iA];
    const float wh1B = Wh1[iB];
    const int   jbase = wave * 32 + q * 8;

    // bitmask: word g = tt*8 + wave/2 covers j in [g*64, g*64+64);
    // our bits sit at (wave&1)*32 + q*8 + idx.
    const unsigned long long* __restrict__ mrowA = mask + (size_t)iA * (NN / 64);
    const unsigned long long* __restrict__ mrowB = mask + (size_t)iB * (NN / 64);
    const int msh = ((wave & 1) << 5) + (q << 3);

    const short8* bp0 = (const short8*)(WhT + (size_t)(0  + il) * NN);
    const short8* bp1 = (const short8*)(WhT + (size_t)(16 + il) * NN);
    const short8* bp2 = (const short8*)(WhT + (size_t)(32 + il) * NN);
    const short8* bp3 = (const short8*)(WhT + (size_t)(48 + il) * NN);

    f32x4 acc0 = {0.f, 0.f, 0.f, 0.f};
    f32x4 acc1 = {0.f, 0.f, 0.f, 0.f};
    f32x4 acc2 = {0.f, 0.f, 0.f, 0.f};
    f32x4 acc3 = {0.f, 0.f, 0.f, 0.f};
    f32x4 acc4 = {0.f, 0.f, 0.f, 0.f};
    f32x4 acc5 = {0.f, 0.f, 0.f, 0.f};
    f32x4 acc6 = {0.f, 0.f, 0.f, 0.f};
    f32x4 acc7 = {0.f, 0.f, 0.f, 0.f};
    float totA = 0.f, totB = 0.f;

#pragma unroll 1
    for (int tt = 0; tt < 16; ++tt) {
        // ---- mask words for this iteration (8 B per row-group, broadcast
        //      across the 16 lanes sharing il) ----
        const int g = (tt << 3) + (wave >> 1);
        const unsigned int bitsA = (unsigned int)(mrowA[g] >> msh) & 0xffu;
        const unsigned int bitsB = (unsigned int)(mrowB[g] >> msh) & 0xffu;

        // ---- JIT Wh2 + B for this iteration ----
        const int j  = jbase + (tt << 9);
        const float4 w20 = *(const float4*)(Wh2 + j);
        const float4 w21 = *(const float4*)(Wh2 + j + 4);
        const int jb = j >> 3;
        const short8 b0 = bp0[jb];
        const short8 b1 = bp1[jb];
        const short8 b2 = bp2[jb];
        const short8 b3 = bp3[jb];

        float wv[8];
#define CALC(idx, bitsv, wh1v, wh2v, totv)                             \
        {                                                              \
            float s = (wh1v) + (wh2v);                                 \
            float e = fmaxf(s, 0.2f * s);      /* leaky_relu 0.2 */    \
            float v = ((bitsv >> idx) & 1u) ? __expf(e) : 0.f;         \
            totv += v;                                                 \
            wv[idx] = v;                                               \
        }
        // ---- row-group A ----
        CALC(0, bitsA, wh1A, w20.x, totA) CALC(1, bitsA, wh1A, w20.y, totA)
        CALC(2, bitsA, wh1A, w20.z, totA) CALC(3, bitsA, wh1A, w20.w, totA)
        CALC(4, bitsA, wh1A, w21.x, totA) CALC(5, bitsA, wh1A, w21.y, totA)
        CALC(6, bitsA, wh1A, w21.z, totA) CALC(7, bitsA, wh1A, w21.w, totA)
        union { short8 v; __hip_bfloat162 h[4]; } afA;
        afA.h[0] = __float22bfloat162_rn(float2{wv[0], wv[1]});
        afA.h[1] = __float22bfloat162_rn(float2{wv[2], wv[3]});
        afA.h[2] = __float22bfloat162_rn(float2{wv[4], wv[5]});
        afA.h[3] = __float22bfloat162_rn(float2{wv[6], wv[7]});

        // ---- row-group B ----
        CALC(0, bitsB, wh1B, w20.x, totB) CALC(1, bitsB, wh1B, w20.y, totB)
        CALC(2, bitsB, wh1B, w20.z, totB) CALC(3, bitsB, wh1B, w20.w, totB)
        CALC(4, bitsB, wh1B, w21.x, totB) CALC(5, bitsB, wh1B, w21.y, totB)
        CALC(6, bitsB, wh1B, w21.z, totB) CALC(7, bitsB, wh1B, w21.w, totB)
#undef CALC
        union { short8 v; __hip_bfloat162 h[4]; } afB;
        afB.h[0] = __float22bfloat162_rn(float2{wv[0], wv[1]});
        afB.h[1] = __float22bfloat162_rn(float2{wv[2], wv[3]});
        afB.h[2] = __float22bfloat162_rn(float2{wv[4], wv[5]});
        afB.h[3] = __float22bfloat162_rn(float2{wv[6], wv[7]});

        // ---- 8 MFMA: both row-groups share B fragments ----
        acc0 = __builtin_amdgcn_mfma_f32_16x16x32_bf16(afA.v, b0, acc0, 0, 0, 0);
        acc1 = __builtin_amdgcn_mfma_f32_16x16x32_bf16(afA.v, b1, acc1, 0, 0, 0);
        acc2 = __builtin_amdgcn_mfma_f32_16x16x32_bf16(afA.v, b2, acc2, 0, 0, 0);
        acc3 = __builtin_amdgcn_mfma_f32_16x16x32_bf16(afA.v, b3, acc3, 0, 0, 0);
        acc4 = __builtin_amdgcn_mfma_f32_16x16x32_bf16(afB.v, b0, acc4, 0, 0, 0);
        acc5 = __builtin_amdgcn_mfma_f32_16x16x32_bf16(afB.v, b1, acc5, 0, 0, 0);
        acc6 = __builtin_amdgcn_mfma_f32_16x16x32_bf16(afB.v, b2, acc6, 0, 0, 0);
        acc7 = __builtin_amdgcn_mfma_f32_16x16x32_bf16(afB.v, b3, acc7, 0, 0, 0);
    }

    // row-total reduction: lanes {il, il+16, il+32, il+48} hold partials
    totA += __shfl_xor(totA, 16, 64);
    totA += __shfl_xor(totA, 32, 64);
    totB += __shfl_xor(totB, 16, 64);
    totB += __shfl_xor(totB, 32, 64);
    if (lane < 16) {
        lds_tot[wave][lane]      = totA;
        lds_tot[wave][16 + lane] = totB;
    }

    // C/D layout: col = lane&15 (f within tile), row = q*4 + reg (i)
#pragma unroll
    for (int r = 0; r < 4; ++r) {
        lds_C[wave][q * 4 + r][0 * 16 + il] = acc0[r];
        lds_C[wave][q * 4 + r][1 * 16 + il] = acc1[r];
        lds_C[wave][q * 4 + r][2 * 16 + il] = acc2[r];
        lds_C[wave][q * 4 + r][3 * 16 + il] = acc3[r];
        lds_C[wave][16 + q * 4 + r][0 * 16 + il] = acc4[r];
        lds_C[wave][16 + q * 4 + r][1 * 16 + il] = acc5[r];
        lds_C[wave][16 + q * 4 + r][2 * 16 + il] = acc6[r];
        lds_C[wave][16 + q * 4 + r][3 * 16 + il] = acc7[r];
    }
    __syncthreads();

    // epilogue: 16-wave reduce, normalize, ELU, final store (2048 outputs)
#pragma unroll
    for (int e = 0; e < 2; ++e) {
        const int idx = e * 1024 + tid;         // over 32*64 outputs
        const int ii = idx >> 6;
        const int ff = idx & 63;
        float s = 0.f;
        float t = 0.f;
#pragma unroll
        for (int w = 0; w < 16; ++w) {
            s += lds_C[w][ii][ff];
            t += lds_tot[w][ii];
        }
        const float p = s / t;
        out[(size_t)(i0 + ii) * FOUT + ff] = (p > 0.f) ? p : (__expf(p) - 1.f);
    }
}

extern "C" void kernel_launch(void* const* d_in, const int* in_sizes, int n_in,
                              void* d_out, int out_size, void* d_ws, size_t ws_size,
                              hipStream_t stream) {
    const float* x   = (const float*)d_in[0];
    const int*   adj = (const int*)d_in[1];
    const float* W   = (const float*)d_in[2];
    const float* a   = (const float*)d_in[3];
    float* out = (float*)d_out;

    char* ws = (char*)d_ws;
    unsigned short* WhT = (unsigned short*)ws;                 // 1 MB @ 0
    float* Wh1  = (float*)(ws + (size_t)1048576);              // 32 KB
    float* Wh2  = (float*)(ws + (size_t)1048576 + 32768);      // 32 KB
    unsigned long long* mask =
        (unsigned long long*)(ws + (size_t)2097152);           // 8 MB @ 2 MB

    gat_prep<<<dim3(NN / 4), dim3(256), 0, stream>>>(x, W, a, WhT, Wh1, Wh2);
    gat_pack<<<dim3(2048), dim3(256), 0, stream>>>(adj, mask);
    gat_attn<<<dim3(NN / 32), dim3(1024), 0, stream>>>(mask, WhT, Wh1, Wh2, out);
}